// Round 2
// baseline (794.315 us; speedup 1.0000x reference)
//
#include <hip/hip_runtime.h>
#include <stdint.h>

// Problem constants
#define M_ROWS 256
#define K_DIM  2048
#define N_FEAT 65536
#define P_PROTO 4096
#define INV_T  20.0f      // 1/0.05
#define N_CLS  69632.0f   // P + N
#define BK 32
#define NT 64
#define NBLK (N_FEAT / NT)   // 1024 gemm blocks

typedef __attribute__((ext_vector_type(8))) __bf16 bf16x8;
typedef __attribute__((ext_vector_type(4))) float  f32x4;

__device__ __forceinline__ unsigned short f2bf_rne(float f) {
    unsigned int u = __float_as_uint(f);
    u += 0x7fffu + ((u >> 16) & 1u);
    return (unsigned short)(u >> 16);
}
__device__ __forceinline__ float bf2f(unsigned short u) {
    return __uint_as_float(((unsigned int)u) << 16);
}

// ---------------------------------------------------------------------------
// Kernel 1: L2-normalize rows of inputs [256 x 2048] fp32 -> bf16 (bit-stored)
// ---------------------------------------------------------------------------
__global__ __launch_bounds__(256) void prep_norm(const float* __restrict__ in,
                                                 unsigned short* __restrict__ xb) {
    const int row = blockIdx.x;
    const int tid = threadIdx.x;
    const float4* r = (const float4*)(in + (size_t)row * K_DIM);
    float4 v0 = r[tid];
    float4 v1 = r[tid + 256];
    float ss = v0.x*v0.x + v0.y*v0.y + v0.z*v0.z + v0.w*v0.w
             + v1.x*v1.x + v1.y*v1.y + v1.z*v1.z + v1.w*v1.w;
    #pragma unroll
    for (int off = 32; off; off >>= 1) ss += __shfl_down(ss, off, 64);
    __shared__ float wsum[4];
    if ((tid & 63) == 0) wsum[tid >> 6] = ss;
    __syncthreads();
    float scale = rsqrtf(wsum[0] + wsum[1] + wsum[2] + wsum[3]);

    ushort4 o0, o1;
    o0.x = f2bf_rne(v0.x * scale); o0.y = f2bf_rne(v0.y * scale);
    o0.z = f2bf_rne(v0.z * scale); o0.w = f2bf_rne(v0.w * scale);
    o1.x = f2bf_rne(v1.x * scale); o1.y = f2bf_rne(v1.y * scale);
    o1.z = f2bf_rne(v1.z * scale); o1.w = f2bf_rne(v1.w * scale);
    ushort4* o = (ushort4*)(xb + (size_t)row * K_DIM);
    o[tid]       = o0;
    o[tid + 256] = o1;
}

// ---------------------------------------------------------------------------
// Kernel 2: target-logit dot products: td[row] = dot(xbf[row], bf(feat[t]))
// one block per row; emulates MFMA numerics (bf16 inputs, fp32 accumulate)
// ---------------------------------------------------------------------------
__global__ __launch_bounds__(256) void tdot(const unsigned short* __restrict__ xb,
                                            const float* __restrict__ feat,
                                            const int* __restrict__ targets,
                                            float* __restrict__ td) {
    const int row = blockIdx.x;
    const int tid = threadIdx.x;
    const int t = targets[row];
    const ushort4* xr = (const ushort4*)(xb + (size_t)row * K_DIM);
    const float4*  fr = (const float4*)(feat + (size_t)t * K_DIM);
    ushort4 xa = xr[tid * 2], xc = xr[tid * 2 + 1];
    float4  fa = fr[tid * 2], fc = fr[tid * 2 + 1];
    float d = bf2f(xa.x) * bf2f(f2bf_rne(fa.x))
            + bf2f(xa.y) * bf2f(f2bf_rne(fa.y))
            + bf2f(xa.z) * bf2f(f2bf_rne(fa.z))
            + bf2f(xa.w) * bf2f(f2bf_rne(fa.w))
            + bf2f(xc.x) * bf2f(f2bf_rne(fc.x))
            + bf2f(xc.y) * bf2f(f2bf_rne(fc.y))
            + bf2f(xc.z) * bf2f(f2bf_rne(fc.z))
            + bf2f(xc.w) * bf2f(f2bf_rne(fc.w));
    #pragma unroll
    for (int off = 32; off; off >>= 1) d += __shfl_down(d, off, 64);
    __shared__ float ws[4];
    if ((tid & 63) == 0) ws[tid >> 6] = d;
    __syncthreads();
    if (tid == 0) td[row] = ws[0] + ws[1] + ws[2] + ws[3];
}

// ---------------------------------------------------------------------------
// Kernel 3: fused GEMM + per-block softmax partials.
// C-tile [256 x 64] never leaves registers; per row we emit
// (max, sumexp-rel-max, sum) over this block's 64 columns (logits = val*20).
// ---------------------------------------------------------------------------
__global__ __launch_bounds__(256) void gemm_fused(const unsigned short* __restrict__ xb,
                                                  const float* __restrict__ feat,
                                                  float* __restrict__ Pm,
                                                  float* __restrict__ Ps,
                                                  float* __restrict__ Psum) {
    __shared__ unsigned short lA[M_ROWS * BK];  // 16 KB
    __shared__ unsigned short lB[NT * BK];      // 4 KB

    const int tid = threadIdx.x;
    const int w   = tid >> 6;
    const int l   = tid & 63;
    const int lr  = l & 15;
    const int lq  = l >> 4;
    const int n0  = blockIdx.x * NT;

    const unsigned short* agp = xb + (size_t)(w * 64 + (l >> 2)) * K_DIM + (l & 3) * 8;
    const int bn = tid >> 2;
    const int bc = tid & 3;
    const float* fptr = feat + (size_t)(n0 + bn) * K_DIM + bc * 8;
    unsigned short* lbdst = lB + bn * BK + bc * 8;

    const unsigned short* aptr = lA + (size_t)((w * 4) * 16 + lr) * BK + lq * 8;
    const unsigned short* bptr = lB + (size_t)lr * BK + lq * 8;

    f32x4 acc[4][4];
    #pragma unroll
    for (int i = 0; i < 4; ++i)
        #pragma unroll
        for (int j = 0; j < 4; ++j)
            acc[i][j] = (f32x4){0.f, 0.f, 0.f, 0.f};

    for (int kt = 0; kt < K_DIM / BK; ++kt) {
        __syncthreads();
        #pragma unroll
        for (int t = 0; t < 4; ++t) {
            __builtin_amdgcn_global_load_lds(
                (const __attribute__((address_space(1))) void*)(agp + (size_t)t * 16 * K_DIM),
                (__attribute__((address_space(3))) void*)((char*)lA + w * 4096 + t * 1024),
                16, 0, 0);
        }
        float4 f0 = *(const float4*)(fptr);
        float4 f1 = *(const float4*)(fptr + 4);
        uint4 pk;
        pk.x = (unsigned)f2bf_rne(f0.x) | ((unsigned)f2bf_rne(f0.y) << 16);
        pk.y = (unsigned)f2bf_rne(f0.z) | ((unsigned)f2bf_rne(f0.w) << 16);
        pk.z = (unsigned)f2bf_rne(f1.x) | ((unsigned)f2bf_rne(f1.y) << 16);
        pk.w = (unsigned)f2bf_rne(f1.z) | ((unsigned)f2bf_rne(f1.w) << 16);
        *(uint4*)lbdst = pk;
        agp  += BK;
        fptr += BK;
        __syncthreads();

        bf16x8 a[4], b[4];
        #pragma unroll
        for (int i = 0; i < 4; ++i) a[i] = *(const bf16x8*)(aptr + (size_t)i * 16 * BK);
        #pragma unroll
        for (int j = 0; j < 4; ++j) b[j] = *(const bf16x8*)(bptr + (size_t)j * 16 * BK);
        #pragma unroll
        for (int i = 0; i < 4; ++i)
            #pragma unroll
            for (int j = 0; j < 4; ++j)
                acc[i][j] = __builtin_amdgcn_mfma_f32_16x16x32_bf16(a[i], b[j], acc[i][j], 0, 0, 0);
    }

    // --- fused epilogue: per-row (max, sumexp, sum) over 64 cols ---
    // lane holds rows (w*4+i)*16 + lq*4 + r at cols j*16+lr; 16 lanes (lr) x 4 j = 64 cols
    #pragma unroll
    for (int i = 0; i < 4; ++i) {
        #pragma unroll
        for (int r = 0; r < 4; ++r) {
            float v0 = acc[i][0][r] * INV_T;
            float v1 = acc[i][1][r] * INV_T;
            float v2 = acc[i][2][r] * INV_T;
            float v3 = acc[i][3][r] * INV_T;
            float mx = fmaxf(fmaxf(v0, v1), fmaxf(v2, v3));
            #pragma unroll
            for (int msk = 1; msk < 16; msk <<= 1)
                mx = fmaxf(mx, __shfl_xor(mx, msk, 16));
            float s  = __expf(v0 - mx) + __expf(v1 - mx) + __expf(v2 - mx) + __expf(v3 - mx);
            float sm = v0 + v1 + v2 + v3;
            #pragma unroll
            for (int msk = 1; msk < 16; msk <<= 1) {
                s  += __shfl_xor(s,  msk, 16);
                sm += __shfl_xor(sm, msk, 16);
            }
            if (lr == 0) {
                const int row = (w * 4 + i) * 16 + lq * 4 + r;
                const size_t idx = (size_t)row * NBLK + blockIdx.x;
                Pm[idx] = mx; Ps[idx] = s; Psum[idx] = sm;
            }
        }
    }
}

// ---------------------------------------------------------------------------
// Kernel 4: per-row merge of 1024 partials + prototype part -> rowvals
// ---------------------------------------------------------------------------
__global__ __launch_bounds__(256) void row_final(const float* __restrict__ proto,
                                                 const float* __restrict__ Pm,
                                                 const float* __restrict__ Ps,
                                                 const float* __restrict__ Psum,
                                                 const float* __restrict__ td,
                                                 float* __restrict__ rowvals) {
    const int row = blockIdx.x;
    const int tid = threadIdx.x;
    float m = -1.0e30f, s = 0.0f, sum = 0.0f;

    const float* pm = Pm   + (size_t)row * NBLK;
    const float* ps = Ps   + (size_t)row * NBLK;
    const float* pu = Psum + (size_t)row * NBLK;
    #pragma unroll
    for (int k = 0; k < NBLK / 256; ++k) {
        const int b = tid + k * 256;
        float mb = pm[b], sb = ps[b];
        float nm = fmaxf(m, mb);
        s = s * __expf(m - nm) + sb * __expf(mb - nm);
        m = nm;
        sum += pu[b];
    }
    const float4* p4 = (const float4*)(proto + (size_t)row * P_PROTO);
    #pragma unroll
    for (int k = 0; k < P_PROTO / 4 / 256; ++k) {
        float4 v = p4[tid + k * 256];
        float a0 = v.x * INV_T, a1 = v.y * INV_T, a2 = v.z * INV_T, a3 = v.w * INV_T;
        float lm = fmaxf(fmaxf(a0, a1), fmaxf(a2, a3));
        float nm = fmaxf(m, lm);
        s = s * __expf(m - nm)
          + __expf(a0 - nm) + __expf(a1 - nm) + __expf(a2 - nm) + __expf(a3 - nm);
        m = nm;
        sum += a0 + a1 + a2 + a3;
    }

    __shared__ float rm[256], rs[256], rsum[256];
    rm[tid] = m; rs[tid] = s; rsum[tid] = sum;
    __syncthreads();
    #pragma unroll
    for (int off = 128; off; off >>= 1) {
        if (tid < off) {
            float m2 = rm[tid + off], s2 = rs[tid + off];
            float nm = fmaxf(rm[tid], m2);
            rs[tid] = rs[tid] * __expf(rm[tid] - nm) + s2 * __expf(m2 - nm);
            rm[tid] = nm;
            rsum[tid] += rsum[tid + off];
        }
        __syncthreads();
    }
    if (tid == 0) {
        const float lse = rm[0] + __logf(rs[0]);
        const float lt  = td[row] * INV_T;
        rowvals[row] = lse - 0.9f * lt - 0.1f * (rsum[0] / N_CLS);
    }
}

// ---------------------------------------------------------------------------
// Kernel 5: mean of 256 rowvals -> scalar loss
// ---------------------------------------------------------------------------
__global__ __launch_bounds__(256) void final_mean(const float* __restrict__ rowvals,
                                                  float* __restrict__ out) {
    const int tid = threadIdx.x;
    float v = rowvals[tid];
    #pragma unroll
    for (int off = 32; off; off >>= 1) v += __shfl_down(v, off, 64);
    __shared__ float ws[4];
    if ((tid & 63) == 0) ws[tid >> 6] = v;
    __syncthreads();
    if (tid == 0) out[0] = (ws[0] + ws[1] + ws[2] + ws[3]) * (1.0f / 256.0f);
}

// ---------------------------------------------------------------------------
extern "C" void kernel_launch(void* const* d_in, const int* in_sizes, int n_in,
                              void* d_out, int out_size, void* d_ws, size_t ws_size,
                              hipStream_t stream) {
    const float* inputs  = (const float*)d_in[0];
    const int*   targets = (const int*)d_in[1];
    const float* proto   = (const float*)d_in[2];
    const float* feat    = (const float*)d_in[3];

    // workspace layout (all sizes in bytes)
    char* ws = (char*)d_ws;
    unsigned short* xb = (unsigned short*)ws;                 // 1 MB  [0, 1M)
    float* Pm      = (float*)(ws + (1u << 20));               // 1 MB  [1M, 2M)
    float* Ps      = (float*)(ws + (2u << 20));               // 1 MB  [2M, 3M)
    float* Psum    = (float*)(ws + (3u << 20));               // 1 MB  [3M, 4M)
    float* td      = (float*)(ws + (4u << 20));               // 1 KB
    float* rowvals = (float*)(ws + (4u << 20) + 4096);        // 1 KB
    float* out     = (float*)d_out;

    prep_norm <<<M_ROWS, 256, 0, stream>>>(inputs, xb);
    tdot      <<<M_ROWS, 256, 0, stream>>>(xb, feat, targets, td);
    gemm_fused<<<NBLK,   256, 0, stream>>>(xb, feat, Pm, Ps, Psum);
    row_final <<<M_ROWS, 256, 0, stream>>>(proto, Pm, Ps, Psum, td, rowvals);
    final_mean<<<1,      256, 0, stream>>>(rowvals, out);
}

// Round 3
// 738.128 us; speedup vs baseline: 1.0761x; 1.0761x over previous
//
#include <hip/hip_runtime.h>
#include <stdint.h>

// Problem constants
#define M_ROWS 256
#define K_DIM  2048
#define N_FEAT 65536
#define P_PROTO 4096
#define INV_T  20.0f      // 1/0.05
#define N_CLS  69632.0f   // P + N
#define BK 64
#define NT 64
#define NBLK (N_FEAT / NT)   // 1024 gemm blocks

typedef __attribute__((ext_vector_type(8))) __bf16 bf16x8;
typedef __attribute__((ext_vector_type(4))) float  f32x4;

__device__ __forceinline__ unsigned short f2bf_rne(float f) {
    unsigned int u = __float_as_uint(f);
    u += 0x7fffu + ((u >> 16) & 1u);
    return (unsigned short)(u >> 16);
}
__device__ __forceinline__ float bf2f(unsigned short u) {
    return __uint_as_float(((unsigned int)u) << 16);
}

// ---------------------------------------------------------------------------
// Kernel 1: L2-normalize inputs row -> bf16 xb, AND target-logit dot
// td[row] = dot(bf16(x_norm[row]), bf16(feat[targets[row]]))  (fp32 accum)
// one block per row, 256 threads
// ---------------------------------------------------------------------------
__global__ __launch_bounds__(256) void prep_tdot(const float* __restrict__ in,
                                                 const float* __restrict__ feat,
                                                 const int* __restrict__ targets,
                                                 unsigned short* __restrict__ xb,
                                                 float* __restrict__ td) {
    const int row = blockIdx.x;
    const int tid = threadIdx.x;
    const float4* r = (const float4*)(in + (size_t)row * K_DIM);
    float4 v0 = r[tid];
    float4 v1 = r[tid + 256];
    float ss = v0.x*v0.x + v0.y*v0.y + v0.z*v0.z + v0.w*v0.w
             + v1.x*v1.x + v1.y*v1.y + v1.z*v1.z + v1.w*v1.w;
    #pragma unroll
    for (int off = 32; off; off >>= 1) ss += __shfl_down(ss, off, 64);
    __shared__ float wsum[4];
    if ((tid & 63) == 0) wsum[tid >> 6] = ss;
    __syncthreads();
    float scale = rsqrtf(wsum[0] + wsum[1] + wsum[2] + wsum[3]);

    ushort4 o0, o1;
    o0.x = f2bf_rne(v0.x * scale); o0.y = f2bf_rne(v0.y * scale);
    o0.z = f2bf_rne(v0.z * scale); o0.w = f2bf_rne(v0.w * scale);
    o1.x = f2bf_rne(v1.x * scale); o1.y = f2bf_rne(v1.y * scale);
    o1.z = f2bf_rne(v1.z * scale); o1.w = f2bf_rne(v1.w * scale);
    ushort4* o = (ushort4*)(xb + (size_t)row * K_DIM);
    o[tid]       = o0;
    o[tid + 256] = o1;

    // --- fused target dot (x already in registers as o0/o1) ---
    const int t = targets[row];
    const float4* fr = (const float4*)(feat + (size_t)t * K_DIM);
    float4 fa = fr[tid];
    float4 fc = fr[tid + 256];
    float d = bf2f(o0.x) * bf2f(f2bf_rne(fa.x))
            + bf2f(o0.y) * bf2f(f2bf_rne(fa.y))
            + bf2f(o0.z) * bf2f(f2bf_rne(fa.z))
            + bf2f(o0.w) * bf2f(f2bf_rne(fa.w))
            + bf2f(o1.x) * bf2f(f2bf_rne(fc.x))
            + bf2f(o1.y) * bf2f(f2bf_rne(fc.y))
            + bf2f(o1.z) * bf2f(f2bf_rne(fc.z))
            + bf2f(o1.w) * bf2f(f2bf_rne(fc.w));
    #pragma unroll
    for (int off = 32; off; off >>= 1) d += __shfl_down(d, off, 64);
    __shared__ float wd[4];
    if ((tid & 63) == 0) wd[tid >> 6] = d;
    __syncthreads();
    if (tid == 0) td[row] = wd[0] + wd[1] + wd[2] + wd[3];
}

// ---------------------------------------------------------------------------
// Kernel 2: fused GEMM + per-block softmax partials. BK=64, NT=64, full M=256.
// XOR-swizzled LDS: logical 16B-chunk c of row r lives at physical c^(r&7).
// Swizzle is applied on the *source* side of global_load_lds (dst is pinned
// to wave-uniform-base + lane*16), and on the write side for B staging.
// ---------------------------------------------------------------------------
__global__ __launch_bounds__(256) void gemm_fused(const unsigned short* __restrict__ xb,
                                                  const float* __restrict__ feat,
                                                  float* __restrict__ Pm,
                                                  float* __restrict__ Ps,
                                                  float* __restrict__ Psum) {
    __shared__ unsigned short lA[M_ROWS * BK];  // 32 KB, 128B rows
    __shared__ unsigned short lB[NT * BK];      // 8 KB, 128B rows

    const int tid = threadIdx.x;
    const int w   = tid >> 6;
    const int l   = tid & 63;
    const int lr  = l & 15;
    const int lq  = l >> 4;
    const int sw  = lr & 7;                 // read-side swizzle key
    const int n0  = blockIdx.x * NT;

    // A staging: inst t of wave w covers LDS rows t*32 + w*8 + (l>>3).
    // lane fetches the globally-swizzled chunk so readers see logical^((row)&7).
    const unsigned short* agp = xb
        + (size_t)(w * 8 + (l >> 3)) * K_DIM
        + (((l & 7) ^ ((l >> 3) & 7)) << 3);

    // B staging: thread -> feature row bn, 16 consecutive fp32 at k-off bc*16
    const int bn = tid >> 2;
    const int bc = tid & 3;
    const float* fptr = feat + (size_t)(n0 + bn) * K_DIM + bc * 16;
    char* lbrow = (char*)lB + bn * 128;
    const int p0 = (((bc * 2)     ^ (bn & 7)) << 4);
    const int p1 = (((bc * 2 + 1) ^ (bn & 7)) << 4);

    const char* lab = (const char*)lA + (size_t)(w * 64 + lr) * 128;
    const char* lbb = (const char*)lB + (size_t)lr * 128;

    f32x4 acc[4][4];
    #pragma unroll
    for (int i = 0; i < 4; ++i)
        #pragma unroll
        for (int j = 0; j < 4; ++j)
            acc[i][j] = (f32x4){0.f, 0.f, 0.f, 0.f};

    for (int kt = 0; kt < K_DIM / BK; ++kt) {   // 32 iterations
        __syncthreads();
        #pragma unroll
        for (int t = 0; t < 8; ++t) {
            __builtin_amdgcn_global_load_lds(
                (const __attribute__((address_space(1))) void*)(agp + (size_t)t * 32 * K_DIM),
                (__attribute__((address_space(3))) void*)((char*)lA + (t * 32 + w * 8) * 128),
                16, 0, 0);
        }
        float4 f0 = *(const float4*)(fptr);
        float4 f1 = *(const float4*)(fptr + 4);
        float4 f2 = *(const float4*)(fptr + 8);
        float4 f3 = *(const float4*)(fptr + 12);
        uint4 ua, ub;
        ua.x = (unsigned)f2bf_rne(f0.x) | ((unsigned)f2bf_rne(f0.y) << 16);
        ua.y = (unsigned)f2bf_rne(f0.z) | ((unsigned)f2bf_rne(f0.w) << 16);
        ua.z = (unsigned)f2bf_rne(f1.x) | ((unsigned)f2bf_rne(f1.y) << 16);
        ua.w = (unsigned)f2bf_rne(f1.z) | ((unsigned)f2bf_rne(f1.w) << 16);
        ub.x = (unsigned)f2bf_rne(f2.x) | ((unsigned)f2bf_rne(f2.y) << 16);
        ub.y = (unsigned)f2bf_rne(f2.z) | ((unsigned)f2bf_rne(f2.w) << 16);
        ub.z = (unsigned)f2bf_rne(f3.x) | ((unsigned)f2bf_rne(f3.y) << 16);
        ub.w = (unsigned)f2bf_rne(f3.z) | ((unsigned)f2bf_rne(f3.w) << 16);
        *(uint4*)(lbrow + p0) = ua;
        *(uint4*)(lbrow + p1) = ub;
        agp  += BK;
        fptr += BK;
        __syncthreads();

        #pragma unroll
        for (int kk = 0; kk < 2; ++kk) {
            const int ct = (((kk * 4 + lq) ^ sw) << 4);   // physical chunk byte offset
            bf16x8 a[4], b[4];
            #pragma unroll
            for (int i = 0; i < 4; ++i) a[i] = *(const bf16x8*)(lab + i * 2048 + ct);
            #pragma unroll
            for (int j = 0; j < 4; ++j) b[j] = *(const bf16x8*)(lbb + j * 2048 + ct);
            #pragma unroll
            for (int i = 0; i < 4; ++i)
                #pragma unroll
                for (int j = 0; j < 4; ++j)
                    acc[i][j] = __builtin_amdgcn_mfma_f32_16x16x32_bf16(a[i], b[j], acc[i][j], 0, 0, 0);
        }
    }

    // --- fused epilogue: per-row (max, sumexp-rel-max, sum) over 64 cols ---
    #pragma unroll
    for (int i = 0; i < 4; ++i) {
        #pragma unroll
        for (int r = 0; r < 4; ++r) {
            float v0 = acc[i][0][r] * INV_T;
            float v1 = acc[i][1][r] * INV_T;
            float v2 = acc[i][2][r] * INV_T;
            float v3 = acc[i][3][r] * INV_T;
            float mx = fmaxf(fmaxf(v0, v1), fmaxf(v2, v3));
            #pragma unroll
            for (int msk = 1; msk < 16; msk <<= 1)
                mx = fmaxf(mx, __shfl_xor(mx, msk, 16));
            float s  = __expf(v0 - mx) + __expf(v1 - mx) + __expf(v2 - mx) + __expf(v3 - mx);
            float sm = v0 + v1 + v2 + v3;
            #pragma unroll
            for (int msk = 1; msk < 16; msk <<= 1) {
                s  += __shfl_xor(s,  msk, 16);
                sm += __shfl_xor(sm, msk, 16);
            }
            if (lr == 0) {
                const int row = (w * 4 + i) * 16 + lq * 4 + r;
                const size_t idx = (size_t)row * NBLK + blockIdx.x;
                Pm[idx] = mx; Ps[idx] = s; Psum[idx] = sm;
            }
        }
    }
}

// ---------------------------------------------------------------------------
// Kernel 3: per-row merge of 1024 partials + prototype part -> rowvals
// ---------------------------------------------------------------------------
__global__ __launch_bounds__(256) void row_final(const float* __restrict__ proto,
                                                 const float* __restrict__ Pm,
                                                 const float* __restrict__ Ps,
                                                 const float* __restrict__ Psum,
                                                 const float* __restrict__ td,
                                                 float* __restrict__ rowvals) {
    const int row = blockIdx.x;
    const int tid = threadIdx.x;
    float m = -1.0e30f, s = 0.0f, sum = 0.0f;

    const float* pm = Pm   + (size_t)row * NBLK;
    const float* ps = Ps   + (size_t)row * NBLK;
    const float* pu = Psum + (size_t)row * NBLK;
    #pragma unroll
    for (int k = 0; k < NBLK / 256; ++k) {
        const int b = tid + k * 256;
        float mb = pm[b], sb = ps[b];
        float nm = fmaxf(m, mb);
        s = s * __expf(m - nm) + sb * __expf(mb - nm);
        m = nm;
        sum += pu[b];
    }
    const float4* p4 = (const float4*)(proto + (size_t)row * P_PROTO);
    #pragma unroll
    for (int k = 0; k < P_PROTO / 4 / 256; ++k) {
        float4 v = p4[tid + k * 256];
        float a0 = v.x * INV_T, a1 = v.y * INV_T, a2 = v.z * INV_T, a3 = v.w * INV_T;
        float lm = fmaxf(fmaxf(a0, a1), fmaxf(a2, a3));
        float nm = fmaxf(m, lm);
        s = s * __expf(m - nm)
          + __expf(a0 - nm) + __expf(a1 - nm) + __expf(a2 - nm) + __expf(a3 - nm);
        m = nm;
        sum += a0 + a1 + a2 + a3;
    }

    __shared__ float rm[256], rs[256], rsum[256];
    rm[tid] = m; rs[tid] = s; rsum[tid] = sum;
    __syncthreads();
    #pragma unroll
    for (int off = 128; off; off >>= 1) {
        if (tid < off) {
            float m2 = rm[tid + off], s2 = rs[tid + off];
            float nm = fmaxf(rm[tid], m2);
            rs[tid] = rs[tid] * __expf(rm[tid] - nm) + s2 * __expf(m2 - nm);
            rm[tid] = nm;
            rsum[tid] += rsum[tid + off];
        }
        __syncthreads();
    }
    if (tid == 0) {
        const float lse = rm[0] + __logf(rs[0]);
        const float lt  = td[row] * INV_T;
        rowvals[row] = lse - 0.9f * lt - 0.1f * (rsum[0] / N_CLS);
    }
}

// ---------------------------------------------------------------------------
// Kernel 4: mean of 256 rowvals -> scalar loss
// ---------------------------------------------------------------------------
__global__ __launch_bounds__(256) void final_mean(const float* __restrict__ rowvals,
                                                  float* __restrict__ out) {
    const int tid = threadIdx.x;
    float v = rowvals[tid];
    #pragma unroll
    for (int off = 32; off; off >>= 1) v += __shfl_down(v, off, 64);
    __shared__ float ws[4];
    if ((tid & 63) == 0) ws[tid >> 6] = v;
    __syncthreads();
    if (tid == 0) out[0] = (ws[0] + ws[1] + ws[2] + ws[3]) * (1.0f / 256.0f);
}

// ---------------------------------------------------------------------------
extern "C" void kernel_launch(void* const* d_in, const int* in_sizes, int n_in,
                              void* d_out, int out_size, void* d_ws, size_t ws_size,
                              hipStream_t stream) {
    const float* inputs  = (const float*)d_in[0];
    const int*   targets = (const int*)d_in[1];
    const float* proto   = (const float*)d_in[2];
    const float* feat    = (const float*)d_in[3];

    // workspace layout (bytes)
    char* ws = (char*)d_ws;
    unsigned short* xb = (unsigned short*)ws;                 // 1 MB  [0, 1M)
    float* Pm      = (float*)(ws + (1u << 20));               // 1 MB
    float* Ps      = (float*)(ws + (2u << 20));               // 1 MB
    float* Psum    = (float*)(ws + (3u << 20));               // 1 MB
    float* td      = (float*)(ws + (4u << 20));               // 1 KB
    float* rowvals = (float*)(ws + (4u << 20) + 4096);        // 1 KB
    float* out     = (float*)d_out;

    prep_tdot <<<M_ROWS, 256, 0, stream>>>(inputs, feat, targets, xb, td);
    gemm_fused<<<NBLK,   256, 0, stream>>>(xb, feat, Pm, Ps, Psum);
    row_final <<<M_ROWS, 256, 0, stream>>>(proto, Pm, Ps, Psum, td, rowvals);
    final_mean<<<1,      256, 0, stream>>>(rowvals, out);
}

// Round 4
// 737.827 us; speedup vs baseline: 1.0766x; 1.0004x over previous
//
#include <hip/hip_runtime.h>
#include <stdint.h>

// Problem constants
#define M_ROWS 256
#define K_DIM  2048
#define N_FEAT 65536
#define P_PROTO 4096
#define INV_T  20.0f      // 1/0.05
#define N_CLS  69632.0f   // P + N
#define BK 64
#define NT 64
#define NBLK (N_FEAT / NT)   // 1024 gemm blocks

typedef __attribute__((ext_vector_type(8))) __bf16 bf16x8;
typedef __attribute__((ext_vector_type(4))) float  f32x4;

__device__ __forceinline__ unsigned short f2bf_rne(float f) {
    unsigned int u = __float_as_uint(f);
    u += 0x7fffu + ((u >> 16) & 1u);
    return (unsigned short)(u >> 16);
}
__device__ __forceinline__ float bf2f(unsigned short u) {
    return __uint_as_float(((unsigned int)u) << 16);
}
// truncating pack of two fp32 -> packed bf16x2 (2 VALU ops)
__device__ __forceinline__ unsigned pk_trunc(float lo, float hi) {
    return (__float_as_uint(lo) >> 16) | (__float_as_uint(hi) & 0xFFFF0000u);
}
// truncate fp32 to bf16 value (as fp32) — matches pk_trunc numerics
__device__ __forceinline__ float trunc_bf(float f) {
    return __uint_as_float(__float_as_uint(f) & 0xFFFF0000u);
}

// ---------------------------------------------------------------------------
// Kernel 1: L2-normalize inputs row -> bf16 xb (RNE), AND target-logit dot
// td[row] = dot(bf16(x_norm[row]), trunc_bf16(feat[targets[row]]))
// ---------------------------------------------------------------------------
__global__ __launch_bounds__(256) void prep_tdot(const float* __restrict__ in,
                                                 const float* __restrict__ feat,
                                                 const int* __restrict__ targets,
                                                 unsigned short* __restrict__ xb,
                                                 float* __restrict__ td) {
    const int row = blockIdx.x;
    const int tid = threadIdx.x;
    const float4* r = (const float4*)(in + (size_t)row * K_DIM);
    float4 v0 = r[tid];
    float4 v1 = r[tid + 256];
    float ss = v0.x*v0.x + v0.y*v0.y + v0.z*v0.z + v0.w*v0.w
             + v1.x*v1.x + v1.y*v1.y + v1.z*v1.z + v1.w*v1.w;
    #pragma unroll
    for (int off = 32; off; off >>= 1) ss += __shfl_down(ss, off, 64);
    __shared__ float wsum[4];
    if ((tid & 63) == 0) wsum[tid >> 6] = ss;
    __syncthreads();
    float scale = rsqrtf(wsum[0] + wsum[1] + wsum[2] + wsum[3]);

    ushort4 o0, o1;
    o0.x = f2bf_rne(v0.x * scale); o0.y = f2bf_rne(v0.y * scale);
    o0.z = f2bf_rne(v0.z * scale); o0.w = f2bf_rne(v0.w * scale);
    o1.x = f2bf_rne(v1.x * scale); o1.y = f2bf_rne(v1.y * scale);
    o1.z = f2bf_rne(v1.z * scale); o1.w = f2bf_rne(v1.w * scale);
    ushort4* o = (ushort4*)(xb + (size_t)row * K_DIM);
    o[tid]       = o0;
    o[tid + 256] = o1;

    // --- fused target dot ---
    const int t = targets[row];
    const float4* fr = (const float4*)(feat + (size_t)t * K_DIM);
    float4 fa = fr[tid];
    float4 fc = fr[tid + 256];
    float d = bf2f(o0.x) * trunc_bf(fa.x)
            + bf2f(o0.y) * trunc_bf(fa.y)
            + bf2f(o0.z) * trunc_bf(fa.z)
            + bf2f(o0.w) * trunc_bf(fa.w)
            + bf2f(o1.x) * trunc_bf(fc.x)
            + bf2f(o1.y) * trunc_bf(fc.y)
            + bf2f(o1.z) * trunc_bf(fc.z)
            + bf2f(o1.w) * trunc_bf(fc.w);
    #pragma unroll
    for (int off = 32; off; off >>= 1) d += __shfl_down(d, off, 64);
    __shared__ float wd[4];
    if ((tid & 63) == 0) wd[tid >> 6] = d;
    __syncthreads();
    if (tid == 0) td[row] = wd[0] + wd[1] + wd[2] + wd[3];
}

// ---------------------------------------------------------------------------
// Kernel 2: fused GEMM + per-block softmax partials. BK=64, NT=64, full M=256.
// XOR-swizzled LDS (chunk c of row r at physical c^(r&7)); truncating bf16
// pack for B staging (2 ops/pair); B tile register-prefetched one iter ahead.
// ---------------------------------------------------------------------------
__global__ __launch_bounds__(256) void gemm_fused(const unsigned short* __restrict__ xb,
                                                  const float* __restrict__ feat,
                                                  float* __restrict__ Pm,
                                                  float* __restrict__ Ps,
                                                  float* __restrict__ Psum) {
    __shared__ unsigned short lA[M_ROWS * BK];  // 32 KB, 128B rows
    __shared__ unsigned short lB[NT * BK];      // 8 KB, 128B rows

    const int tid = threadIdx.x;
    const int w   = tid >> 6;
    const int l   = tid & 63;
    const int lr  = l & 15;
    const int lq  = l >> 4;
    const int sw  = lr & 7;
    const int n0  = blockIdx.x * NT;

    // A staging: inst t of wave w covers LDS rows t*32 + w*8 + (l>>3);
    // source chunk swizzled so readers see logical^(row&7).
    const unsigned short* agp = xb
        + (size_t)(w * 8 + (l >> 3)) * K_DIM
        + (((l & 7) ^ ((l >> 3) & 7)) << 3);

    // B staging: thread -> feature row bn, 16 consecutive fp32 at k-off bc*16
    const int bn = tid >> 2;
    const int bc = tid & 3;
    const float* fptr = feat + (size_t)(n0 + bn) * K_DIM + bc * 16;
    char* lbrow = (char*)lB + bn * 128;
    const int p0 = (((bc * 2)     ^ (bn & 7)) << 4);
    const int p1 = (((bc * 2 + 1) ^ (bn & 7)) << 4);

    const char* lab = (const char*)lA + (size_t)(w * 64 + lr) * 128;
    const char* lbb = (const char*)lB + (size_t)lr * 128;

    f32x4 acc[4][4];
    #pragma unroll
    for (int i = 0; i < 4; ++i)
        #pragma unroll
        for (int j = 0; j < 4; ++j)
            acc[i][j] = (f32x4){0.f, 0.f, 0.f, 0.f};

    // prefetch B tile for iter 0
    float4 f0 = *(const float4*)(fptr);
    float4 f1 = *(const float4*)(fptr + 4);
    float4 f2 = *(const float4*)(fptr + 8);
    float4 f3 = *(const float4*)(fptr + 12);

    for (int kt = 0; kt < K_DIM / BK; ++kt) {   // 32 iterations
        __syncthreads();
        #pragma unroll
        for (int t = 0; t < 8; ++t) {
            __builtin_amdgcn_global_load_lds(
                (const __attribute__((address_space(1))) void*)(agp + (size_t)t * 32 * K_DIM),
                (__attribute__((address_space(3))) void*)((char*)lA + (t * 32 + w * 8) * 128),
                16, 0, 0);
        }
        // pack current B tile from regs (truncating, 2 ops/pair)
        uint4 ua, ub;
        ua.x = pk_trunc(f0.x, f0.y);
        ua.y = pk_trunc(f0.z, f0.w);
        ua.z = pk_trunc(f1.x, f1.y);
        ua.w = pk_trunc(f1.z, f1.w);
        ub.x = pk_trunc(f2.x, f2.y);
        ub.y = pk_trunc(f2.z, f2.w);
        ub.z = pk_trunc(f3.x, f3.y);
        ub.w = pk_trunc(f3.z, f3.w);
        *(uint4*)(lbrow + p0) = ua;
        *(uint4*)(lbrow + p1) = ub;
        agp += BK;
        // prefetch next B tile
        if (kt + 1 < K_DIM / BK) {
            fptr += BK;
            f0 = *(const float4*)(fptr);
            f1 = *(const float4*)(fptr + 4);
            f2 = *(const float4*)(fptr + 8);
            f3 = *(const float4*)(fptr + 12);
        }
        __syncthreads();

        #pragma unroll
        for (int kk = 0; kk < 2; ++kk) {
            const int ct = (((kk * 4 + lq) ^ sw) << 4);
            bf16x8 a[4], b[4];
            #pragma unroll
            for (int i = 0; i < 4; ++i) a[i] = *(const bf16x8*)(lab + i * 2048 + ct);
            #pragma unroll
            for (int j = 0; j < 4; ++j) b[j] = *(const bf16x8*)(lbb + j * 2048 + ct);
            #pragma unroll
            for (int i = 0; i < 4; ++i)
                #pragma unroll
                for (int j = 0; j < 4; ++j)
                    acc[i][j] = __builtin_amdgcn_mfma_f32_16x16x32_bf16(a[i], b[j], acc[i][j], 0, 0, 0);
        }
    }

    // --- fused epilogue: per-row (max, sumexp-rel-max, sum) over 64 cols ---
    #pragma unroll
    for (int i = 0; i < 4; ++i) {
        #pragma unroll
        for (int r = 0; r < 4; ++r) {
            float v0 = acc[i][0][r] * INV_T;
            float v1 = acc[i][1][r] * INV_T;
            float v2 = acc[i][2][r] * INV_T;
            float v3 = acc[i][3][r] * INV_T;
            float mx = fmaxf(fmaxf(v0, v1), fmaxf(v2, v3));
            #pragma unroll
            for (int msk = 1; msk < 16; msk <<= 1)
                mx = fmaxf(mx, __shfl_xor(mx, msk, 16));
            float s  = __expf(v0 - mx) + __expf(v1 - mx) + __expf(v2 - mx) + __expf(v3 - mx);
            float sm = v0 + v1 + v2 + v3;
            #pragma unroll
            for (int msk = 1; msk < 16; msk <<= 1) {
                s  += __shfl_xor(s,  msk, 16);
                sm += __shfl_xor(sm, msk, 16);
            }
            if (lr == 0) {
                const int row = (w * 4 + i) * 16 + lq * 4 + r;
                const size_t idx = (size_t)row * NBLK + blockIdx.x;
                Pm[idx] = mx; Ps[idx] = s; Psum[idx] = sm;
            }
        }
    }
}

// ---------------------------------------------------------------------------
// Kernel 3: per-row merge of 1024 partials + prototype part -> rowvals
// ---------------------------------------------------------------------------
__global__ __launch_bounds__(256) void row_final(const float* __restrict__ proto,
                                                 const float* __restrict__ Pm,
                                                 const float* __restrict__ Ps,
                                                 const float* __restrict__ Psum,
                                                 const float* __restrict__ td,
                                                 float* __restrict__ rowvals) {
    const int row = blockIdx.x;
    const int tid = threadIdx.x;
    float m = -1.0e30f, s = 0.0f, sum = 0.0f;

    const float* pm = Pm   + (size_t)row * NBLK;
    const float* ps = Ps   + (size_t)row * NBLK;
    const float* pu = Psum + (size_t)row * NBLK;
    #pragma unroll
    for (int k = 0; k < NBLK / 256; ++k) {
        const int b = tid + k * 256;
        float mb = pm[b], sb = ps[b];
        float nm = fmaxf(m, mb);
        s = s * __expf(m - nm) + sb * __expf(mb - nm);
        m = nm;
        sum += pu[b];
    }
    const float4* p4 = (const float4*)(proto + (size_t)row * P_PROTO);
    #pragma unroll
    for (int k = 0; k < P_PROTO / 4 / 256; ++k) {
        float4 v = p4[tid + k * 256];
        float a0 = v.x * INV_T, a1 = v.y * INV_T, a2 = v.z * INV_T, a3 = v.w * INV_T;
        float lm = fmaxf(fmaxf(a0, a1), fmaxf(a2, a3));
        float nm = fmaxf(m, lm);
        s = s * __expf(m - nm)
          + __expf(a0 - nm) + __expf(a1 - nm) + __expf(a2 - nm) + __expf(a3 - nm);
        m = nm;
        sum += a0 + a1 + a2 + a3;
    }

    __shared__ float rm[256], rs[256], rsum[256];
    rm[tid] = m; rs[tid] = s; rsum[tid] = sum;
    __syncthreads();
    #pragma unroll
    for (int off = 128; off; off >>= 1) {
        if (tid < off) {
            float m2 = rm[tid + off], s2 = rs[tid + off];
            float nm = fmaxf(rm[tid], m2);
            rs[tid] = rs[tid] * __expf(rm[tid] - nm) + s2 * __expf(m2 - nm);
            rm[tid] = nm;
            rsum[tid] += rsum[tid + off];
        }
        __syncthreads();
    }
    if (tid == 0) {
        const float lse = rm[0] + __logf(rs[0]);
        const float lt  = td[row] * INV_T;
        rowvals[row] = lse - 0.9f * lt - 0.1f * (rsum[0] / N_CLS);
    }
}

// ---------------------------------------------------------------------------
// Kernel 4: mean of 256 rowvals -> scalar loss
// ---------------------------------------------------------------------------
__global__ __launch_bounds__(256) void final_mean(const float* __restrict__ rowvals,
                                                  float* __restrict__ out) {
    const int tid = threadIdx.x;
    float v = rowvals[tid];
    #pragma unroll
    for (int off = 32; off; off >>= 1) v += __shfl_down(v, off, 64);
    __shared__ float ws[4];
    if ((tid & 63) == 0) ws[tid >> 6] = v;
    __syncthreads();
    if (tid == 0) out[0] = (ws[0] + ws[1] + ws[2] + ws[3]) * (1.0f / 256.0f);
}

// ---------------------------------------------------------------------------
extern "C" void kernel_launch(void* const* d_in, const int* in_sizes, int n_in,
                              void* d_out, int out_size, void* d_ws, size_t ws_size,
                              hipStream_t stream) {
    const float* inputs  = (const float*)d_in[0];
    const int*   targets = (const int*)d_in[1];
    const float* proto   = (const float*)d_in[2];
    const float* feat    = (const float*)d_in[3];

    // workspace layout (bytes)
    char* ws = (char*)d_ws;
    unsigned short* xb = (unsigned short*)ws;                 // 1 MB  [0, 1M)
    float* Pm      = (float*)(ws + (1u << 20));               // 1 MB
    float* Ps      = (float*)(ws + (2u << 20));               // 1 MB
    float* Psum    = (float*)(ws + (3u << 20));               // 1 MB
    float* td      = (float*)(ws + (4u << 20));               // 1 KB
    float* rowvals = (float*)(ws + (4u << 20) + 4096);        // 1 KB
    float* out     = (float*)d_out;

    prep_tdot <<<M_ROWS, 256, 0, stream>>>(inputs, feat, targets, xb, td);
    gemm_fused<<<NBLK,   256, 0, stream>>>(xb, feat, Pm, Ps, Psum);
    row_final <<<M_ROWS, 256, 0, stream>>>(proto, Pm, Ps, Psum, td, rowvals);
    final_mean<<<1,      256, 0, stream>>>(rowvals, out);
}